// Round 1
// baseline (428.580 us; speedup 1.0000x reference)
//
#include <hip/hip_runtime.h>
#include <hip/hip_bf16.h>

typedef __bf16 bf16;
typedef __attribute__((ext_vector_type(8))) __bf16 bf16x8;
typedef __attribute__((ext_vector_type(4))) float f32x4;

__device__ __forceinline__ void gload_lds16(const void* g, void* l) {
    __builtin_amdgcn_global_load_lds(
        (const __attribute__((address_space(1))) unsigned int*)g,
        (__attribute__((address_space(3))) unsigned int*)l, 16, 0, 0);
}

// ---------------- prep kernels ----------------

__global__ void sigmoid_kernel(const float* __restrict__ in, float* __restrict__ out, int n) {
    int i = blockIdx.x * 256 + threadIdx.x;
    if (i < n) out[i] = 1.0f / (1.0f + expf(-in[i]));
}

// in: [batch][R][S] fp32 -> out: [batch][S][R] bf16
__global__ void transpose_cvt(const float* __restrict__ in, bf16* __restrict__ out, int R, int S) {
    __shared__ float tile[32][33];
    const int batch = blockIdx.z;
    in  += (size_t)batch * R * S;
    out += (size_t)batch * R * S;
    const int s0 = blockIdx.x * 32, r0 = blockIdx.y * 32;
    const int tx = threadIdx.x & 31, ty = threadIdx.x >> 5; // 32 x 8
#pragma unroll
    for (int i = 0; i < 32; i += 8)
        tile[ty + i][tx] = in[(size_t)(r0 + ty + i) * S + s0 + tx];
    __syncthreads();
#pragma unroll
    for (int i = 0; i < 32; i += 8)
        out[(size_t)(s0 + ty + i) * R + r0 + tx] = (bf16)tile[tx][ty + i];
}

// ---------------- big GEMM with fused masking ----------------
// out[c][b][n] = relu( sum_d (gate[c,d]*x[b,d]+(1-gate[c,d])*mean[d]) * Wt[c?][n][d] + bias[c?][n] )
// K = D = 2048 fixed. BM=BN=128, BK=64, 256 threads (4 waves, 2x2 of 64x64).
__global__ __launch_bounds__(256, 2)
void gemm_masked_relu(const float* __restrict__ x,
                      const float* __restrict__ gate,
                      const float* __restrict__ mean,
                      const bf16* __restrict__ Wt,
                      const float* __restrict__ bias,
                      bf16* __restrict__ out,
                      int N, long wt_cstride, long bias_cstride)
{
    constexpr int ALD = 72;  // padded A leading dim (breaks bank conflicts on A frag reads)
    __shared__ __align__(16) bf16 As[128 * ALD];
    __shared__ __align__(16) bf16 Bs[128 * 64];

    const int c  = blockIdx.z;
    const int m0 = blockIdx.x * 128;
    const int n0 = blockIdx.y * 128;
    const int t  = threadIdx.x;
    const int lane = t & 63, wave = t >> 6;
    const int wr = wave >> 1, wc = wave & 1;

    const bf16*  W   = Wt   + (long)c * wt_cstride;
    const float* gb  = gate + (long)c * 2048;
    const float* bbn = bias + (long)c * bias_cstride + n0;
    bf16* outc = out + ((long)c * 4096 + m0) * N + n0;

    const int sr = t >> 3;        // 0..31
    const int sc = (t & 7) * 8;   // 0..56

    f32x4 acc[4][4] = {};

    for (int kt = 0; kt < 32; ++kt) {
        const int k0 = kt * 64;
        // gate / precomputed (1-g)*mean for this thread's 8 columns
        float4 g0 = *(const float4*)(gb + k0 + sc);
        float4 g1 = *(const float4*)(gb + k0 + sc + 4);
        float4 ma = *(const float4*)(mean + k0 + sc);
        float4 mb = *(const float4*)(mean + k0 + sc + 4);
        float g[8]  = {g0.x, g0.y, g0.z, g0.w, g1.x, g1.y, g1.z, g1.w};
        float mm[8] = {ma.x, ma.y, ma.z, ma.w, mb.x, mb.y, mb.z, mb.w};
        float gm[8];
#pragma unroll
        for (int j = 0; j < 8; ++j) gm[j] = mm[j] - g[j] * mm[j];

        // A: masked on the fly (reg-staged)
#pragma unroll
        for (int i = 0; i < 4; ++i) {
            const int r = i * 32 + sr;
            const float* xp = x + (long)(m0 + r) * 2048 + k0 + sc;
            float4 x0 = *(const float4*)(xp);
            float4 x1 = *(const float4*)(xp + 4);
            float xv[8] = {x0.x, x0.y, x0.z, x0.w, x1.x, x1.y, x1.z, x1.w};
            bf16x8 v;
#pragma unroll
            for (int j = 0; j < 8; ++j) v[j] = (bf16)fmaf(g[j], xv[j], gm[j]);
            *(bf16x8*)&As[r * ALD + sc] = v;
        }
        // B: async direct-to-LDS (linear layout)
#pragma unroll
        for (int i = 0; i < 4; ++i) {
            const bf16* src = W + (long)(n0 + i * 32 + sr) * 2048 + k0 + sc;
            gload_lds16(src, &Bs[i * 2048 + wave * 512]);
        }
        __syncthreads();

#pragma unroll
        for (int kk = 0; kk < 2; ++kk) {
            bf16x8 af[4], bfr[4];
#pragma unroll
            for (int m = 0; m < 4; ++m)
                af[m] = *(const bf16x8*)&As[(wr * 64 + m * 16 + (lane & 15)) * ALD + kk * 32 + (lane >> 4) * 8];
#pragma unroll
            for (int n = 0; n < 4; ++n)
                bfr[n] = *(const bf16x8*)&Bs[(wc * 64 + n * 16 + (lane & 15)) * 64 + kk * 32 + (lane >> 4) * 8];
#pragma unroll
            for (int m = 0; m < 4; ++m)
#pragma unroll
                for (int n = 0; n < 4; ++n)
                    acc[m][n] = __builtin_amdgcn_mfma_f32_16x16x32_bf16(af[m], bfr[n], acc[m][n], 0, 0, 0);
        }
        __syncthreads();
    }

    const int ci = lane & 15, r4 = (lane >> 4) * 4;
#pragma unroll
    for (int m = 0; m < 4; ++m)
#pragma unroll
        for (int n = 0; n < 4; ++n) {
            const int col = wc * 64 + n * 16 + ci;
            const float bv = bbn[col];
#pragma unroll
            for (int j = 0; j < 4; ++j) {
                const int row = wr * 64 + m * 16 + r4 + j;
                float v = acc[m][n][j] + bv;
                v = fmaxf(v, 0.0f);
                outc[(long)row * N + col] = (bf16)v;
            }
        }
}

// ---------------- generic bf16 GEMM (A bf16 buffer, fp32 out) ----------------
// out[(m0+row)*out_rstride + c*out_c_off + col] = [relu](A[c] @ Wt[c]^T + bias[c])
template <int RELU>
__global__ __launch_bounds__(256, 2)
void gemm_bf16_kernel(const bf16* __restrict__ A,
                      const bf16* __restrict__ Wt,
                      const float* __restrict__ bias,
                      float* __restrict__ outf,
                      int K,
                      long a_cstride, long w_cstride, long b_cstride,
                      long out_rstride, long out_c_off)
{
    __shared__ __align__(16) bf16 As[128 * 64];
    __shared__ __align__(16) bf16 Bs[128 * 64];

    const int c  = blockIdx.z;
    const int m0 = blockIdx.x * 128;
    const int n0 = blockIdx.y * 128;
    const int t  = threadIdx.x;
    const int lane = t & 63, wave = t >> 6;
    const int wr = wave >> 1, wc = wave & 1;

    const bf16*  Ac  = A    + (long)c * a_cstride;
    const bf16*  W   = Wt   + (long)c * w_cstride;
    const float* bbn = bias + (long)c * b_cstride + n0;
    float* outp = outf + (long)c * out_c_off + (long)m0 * out_rstride + n0;

    const int sr = t >> 3;
    const int sc = (t & 7) * 8;

    f32x4 acc[4][4] = {};

    for (int kt = 0; kt < K / 64; ++kt) {
        const int k0 = kt * 64;
#pragma unroll
        for (int i = 0; i < 4; ++i)
            gload_lds16(Ac + (long)(m0 + i * 32 + sr) * K + k0 + sc, &As[i * 2048 + wave * 512]);
#pragma unroll
        for (int i = 0; i < 4; ++i)
            gload_lds16(W + (long)(n0 + i * 32 + sr) * K + k0 + sc, &Bs[i * 2048 + wave * 512]);
        __syncthreads();

#pragma unroll
        for (int kk = 0; kk < 2; ++kk) {
            bf16x8 af[4], bfr[4];
#pragma unroll
            for (int m = 0; m < 4; ++m)
                af[m] = *(const bf16x8*)&As[(wr * 64 + m * 16 + (lane & 15)) * 64 + kk * 32 + (lane >> 4) * 8];
#pragma unroll
            for (int n = 0; n < 4; ++n)
                bfr[n] = *(const bf16x8*)&Bs[(wc * 64 + n * 16 + (lane & 15)) * 64 + kk * 32 + (lane >> 4) * 8];
#pragma unroll
            for (int m = 0; m < 4; ++m)
#pragma unroll
                for (int n = 0; n < 4; ++n)
                    acc[m][n] = __builtin_amdgcn_mfma_f32_16x16x32_bf16(af[m], bfr[n], acc[m][n], 0, 0, 0);
        }
        __syncthreads();
    }

    const int ci = lane & 15, r4 = (lane >> 4) * 4;
#pragma unroll
    for (int m = 0; m < 4; ++m)
#pragma unroll
        for (int n = 0; n < 4; ++n) {
            const int col = wc * 64 + n * 16 + ci;
            const float bv = bbn[col];
#pragma unroll
            for (int j = 0; j < 4; ++j) {
                const int row = wr * 64 + m * 16 + r4 + j;
                float v = acc[m][n][j] + bv;
                if (RELU) v = fmaxf(v, 0.0f);
                outp[(long)row * out_rstride + col] = v;
            }
        }
}

// ---------------- fusion: l2-norm over C, concept prob, bottleneck ----------------
// cm, latent: [B][C=16][L=128] fp32.  bott: [B][C*64] bf16.  One wave per row b.
__global__ void fuse_kernel(const float* __restrict__ cm, const float* __restrict__ latent,
                            bf16* __restrict__ bott)
{
    const int wave = threadIdx.x >> 6;
    const int l    = threadIdx.x & 63;
    const int b    = blockIdx.x * 4 + wave;
    const float* cmb  = cm     + (size_t)b * 2048;
    const float* latb = latent + (size_t)b * 2048;

    float sq0 = 0.f, sq1 = 0.f;
#pragma unroll
    for (int c = 0; c < 16; ++c) {
        float v0 = cmb[c * 128 + l], v1 = cmb[c * 128 + 64 + l];
        sq0 += v0 * v0; sq1 += v1 * v1;
    }
    const float rs0 = rsqrtf(fmaxf(sq0, 1e-12f));
    const float rs1 = rsqrtf(fmaxf(sq1, 1e-12f));

#pragma unroll
    for (int c = 0; c < 16; ++c) {
        float cn0 = cmb[c * 128 + l] * rs0;        // col l      (first half)
        float cn1 = cmb[c * 128 + 64 + l] * rs1;   // col 64+l   (second half)
        float part = cn0 * latb[c * 128 + l] + cn1 * latb[c * 128 + 64 + l];
#pragma unroll
        for (int off = 32; off; off >>= 1) part += __shfl_xor(part, off);
        const float p = 1.0f / (1.0f + expf(-part));
        bott[(size_t)b * 1024 + c * 64 + l] = (bf16)(p * cn1 + (1.0f - p) * cn0);
    }
}

// ---------------- final small matmul: logits = z @ Wc + bc ----------------
__global__ void head2_kernel(const float* __restrict__ z, const float* __restrict__ Wc,
                             const float* __restrict__ bc, float* __restrict__ out)
{
    __shared__ float zrow[128];
    const int b = blockIdx.x;
    const int t = threadIdx.x;
    if (t < 128) zrow[t] = z[(size_t)b * 128 + t];
    __syncthreads();
    if (t < 200) {
        float acc = bc[t];
#pragma unroll 8
        for (int k = 0; k < 128; ++k) acc = fmaf(zrow[k], Wc[k * 200 + t], acc);
        out[(size_t)b * 200 + t] = acc;
    }
}

// ---------------- launch ----------------

extern "C" void kernel_launch(void* const* d_in, const int* in_sizes, int n_in,
                              void* d_out, int out_size, void* d_ws, size_t ws_size,
                              hipStream_t stream)
{
    (void)in_sizes; (void)n_in; (void)out_size; (void)ws_size;

    const float* x    = (const float*)d_in[0];
    const float* fp   = (const float*)d_in[1];
    const float* mean = (const float*)d_in[2];
    const float* Wg1  = (const float*)d_in[3];
    const float* bg1  = (const float*)d_in[4];
    const float* Wg2  = (const float*)d_in[5];
    const float* bg2  = (const float*)d_in[6];
    const float* Wf1  = (const float*)d_in[7];
    const float* bf1  = (const float*)d_in[8];
    const float* Wf2  = (const float*)d_in[9];
    const float* bf2  = (const float*)d_in[10];
    const float* Wgh  = (const float*)d_in[11];
    const float* bgh  = (const float*)d_in[12];
    const float* Wc   = (const float*)d_in[13];
    const float* bc   = (const float*)d_in[14];
    float* outp = (float*)d_out;

    char* w = (char*)d_ws;
    size_t off = 0;
    float* gate = (float*)(w + off); off += (size_t)16 * 2048 * 4;        // 128 KB
    bf16* Wg1T  = (bf16*)(w + off);  off += (size_t)16 * 256 * 2048 * 2;  // 16 MB
    bf16* Wg2T  = (bf16*)(w + off);  off += (size_t)16 * 128 * 256 * 2;   // 1 MB
    bf16* Wf1T  = (bf16*)(w + off);  off += (size_t)512 * 2048 * 2;       // 2 MB
    bf16* Wf2T  = (bf16*)(w + off);  off += (size_t)128 * 512 * 2;        // 128 KB
    bf16* WghT  = (bf16*)(w + off);  off += (size_t)128 * 1024 * 2;       // 256 KB
    bf16* h     = (bf16*)(w + off);  off += (size_t)16 * 4096 * 256 * 2;  // 32 MB
    bf16* hf    = (bf16*)(w + off);  off += (size_t)16 * 4096 * 512 * 2;  // 64 MB
    float* cm   = (float*)(w + off); off += (size_t)4096 * 16 * 128 * 4;  // 32 MB
    float* lat  = (float*)(w + off); off += (size_t)4096 * 16 * 128 * 4;  // 32 MB
    bf16* bott  = (bf16*)(w + off);  off += (size_t)4096 * 1024 * 2;      // 8 MB
    float* z    = (float*)(w + off); off += (size_t)4096 * 128 * 4;       // 2 MB
    // total ~190 MB of ws

    // prep
    sigmoid_kernel<<<128, 256, 0, stream>>>(fp, gate, 16 * 2048);
    transpose_cvt<<<dim3(8, 64, 16), 256, 0, stream>>>(Wg1, Wg1T, 2048, 256);
    transpose_cvt<<<dim3(4, 8, 16), 256, 0, stream>>>(Wg2, Wg2T, 256, 128);
    transpose_cvt<<<dim3(16, 64, 1), 256, 0, stream>>>(Wf1, Wf1T, 2048, 512);
    transpose_cvt<<<dim3(4, 16, 1), 256, 0, stream>>>(Wf2, Wf2T, 512, 128);
    transpose_cvt<<<dim3(4, 32, 1), 256, 0, stream>>>(Wgh, WghT, 1024, 128);

    // h = relu(masked @ Wg1 + bg1)   [C][B][256]
    gemm_masked_relu<<<dim3(32, 2, 16), 256, 0, stream>>>(
        x, gate, mean, Wg1T, bg1, h, 256, (long)256 * 2048, 256);
    // hf = relu(masked @ Wf1 + bf1)  [C][B][512]
    gemm_masked_relu<<<dim3(32, 4, 16), 256, 0, stream>>>(
        x, gate, mean, Wf1T, bf1, hf, 512, 0, 0);

    // cm[b][c][l] = h[c] @ Wg2[c] + bg2[c]
    gemm_bf16_kernel<0><<<dim3(32, 1, 16), 256, 0, stream>>>(
        h, Wg2T, bg2, cm, 256, (long)4096 * 256, (long)128 * 256, 128, 2048, 128);
    // latent[b][c][l] = hf[c] @ Wf2 + bf2
    gemm_bf16_kernel<0><<<dim3(32, 1, 16), 256, 0, stream>>>(
        hf, Wf2T, bf2, lat, 512, (long)4096 * 512, 0, 0, 2048, 128);

    // normalize over C, concept prob, bottleneck blend -> bott [B][1024] bf16
    fuse_kernel<<<1024, 256, 0, stream>>>(cm, lat, bott);

    // z = relu(bott @ Wg_head + bg_head)  [B][128] fp32
    gemm_bf16_kernel<1><<<dim3(32, 1, 1), 256, 0, stream>>>(
        bott, WghT, bgh, z, 1024, 0, 0, 0, 128, 0);

    // logits = z @ Wc + bc
    head2_kernel<<<4096, 256, 0, stream>>>(z, Wc, bc, outp);
}

// Round 2
// 405.336 us; speedup vs baseline: 1.0573x; 1.0573x over previous
//
#include <hip/hip_runtime.h>
#include <hip/hip_bf16.h>

typedef __bf16 bf16;
typedef __attribute__((ext_vector_type(8))) __bf16 bf16x8;
typedef __attribute__((ext_vector_type(4))) float f32x4;

__device__ __forceinline__ void gload_lds16(const void* g, void* l) {
    __builtin_amdgcn_global_load_lds(
        (const __attribute__((address_space(1))) unsigned int*)g,
        (__attribute__((address_space(3))) unsigned int*)l, 16, 0, 0);
}

#define BARRIER()   asm volatile("s_barrier" ::: "memory")
#define WAITLGKM0() asm volatile("s_waitcnt lgkmcnt(0)" ::: "memory")
#define WAITVM4()   asm volatile("s_waitcnt vmcnt(4)" ::: "memory")

// ---------------- prep kernels ----------------

__global__ void sigmoid_kernel(const float* __restrict__ in, float* __restrict__ out, int n) {
    int i = blockIdx.x * 256 + threadIdx.x;
    if (i < n) out[i] = 1.0f / (1.0f + expf(-in[i]));
}

__global__ void cvt_x(const float* __restrict__ in, bf16* __restrict__ out) {
    const long i = ((long)blockIdx.x * 256 + threadIdx.x) * 8;
    float4 v0 = *(const float4*)(in + i);
    float4 v1 = *(const float4*)(in + i + 4);
    bf16x8 o;
    o[0]=(bf16)v0.x; o[1]=(bf16)v0.y; o[2]=(bf16)v0.z; o[3]=(bf16)v0.w;
    o[4]=(bf16)v1.x; o[5]=(bf16)v1.y; o[6]=(bf16)v1.z; o[7]=(bf16)v1.w;
    *(bf16x8*)(out + i) = o;
}

// in: [z][R][S] fp32 -> out: [batch][S][R] bf16, scaled by gate[batch][R];
// also accumulates corr[batch][s] += sum_r (1-g)*mean[r]*W[r][s]  (atomic).
template <int SCALED, int NB>
__global__ void prep_w(const float* __restrict__ in, bf16* __restrict__ out,
                       int R, int S, long in_bstride, long out_bstride,
                       const float* __restrict__ gate, const float* __restrict__ mean,
                       float* __restrict__ corr)
{
    __shared__ float tile[32][33];
    const int s0 = blockIdx.x * 32, r0 = blockIdx.y * 32;
    const int tx = threadIdx.x & 31, ty = threadIdx.x >> 5;
    const float* inb = in + (long)blockIdx.z * in_bstride;
#pragma unroll
    for (int i = 0; i < 32; i += 8)
        tile[ty + i][tx] = inb[(long)(r0 + ty + i) * S + s0 + tx];
    __syncthreads();
    const float mv = SCALED ? mean[r0 + tx] : 0.f;
#pragma unroll 1
    for (int b2 = 0; b2 < NB; ++b2) {
        const int batch = blockIdx.z * NB + b2;
        bf16* outb = out + (long)batch * out_bstride;
        float gv = 1.f, gmv = 0.f;
        if (SCALED) { gv = gate[(long)batch * R + r0 + tx]; gmv = (1.f - gv) * mv; }
#pragma unroll
        for (int i = 0; i < 32; i += 8) {
            const float wv = tile[tx][ty + i];
            outb[(long)(s0 + ty + i) * R + r0 + tx] = (bf16)(gv * wv);
            if (SCALED) {
                float v = gmv * wv;
#pragma unroll
                for (int off = 16; off; off >>= 1) v += __shfl_xor(v, off);
                if (tx == 0) atomicAdd(&corr[(long)batch * S + s0 + ty + i], v);
            }
        }
    }
}

// ---------------- 256x256 8-phase bf16 GEMM (K=2048) ----------------
// out[c][row][col] = relu( A[row,:] . B[c][col,:] + bias[c?][col] + corr[c][col] )
__global__ __launch_bounds__(512, 2)
void gemm256(const bf16* __restrict__ A, const bf16* __restrict__ Bw,
             const float* __restrict__ bias, const float* __restrict__ corr,
             bf16* __restrict__ out, int N,
             long b_cstride, long bias_cstride, long corr_cstride)
{
    __shared__ __align__(16) bf16 lds[2][4][8192];  // [buf][A0,A1,B0,B1][128*64]
    const int c = blockIdx.z;
    const int m0 = blockIdx.x * 256, n0 = blockIdx.y * 256;
    const int t = threadIdx.x, lane = t & 63, w = t >> 6;
    const int wr = w >> 2, wc = w & 3;
    const bf16* Bc = Bw + (long)c * b_cstride;

    // staging: lane's 16B chunk -> swizzled global source (q = (lane&7)^(lane>>3))
    const int rr = lane >> 3;
    const int qq = (lane & 7) ^ rr;
    const bf16* pA0 = A  + (long)(m0 + w * 16 + rr) * 2048 + qq * 8;
    const bf16* pA1 = pA0 + 8 * 2048;
    const bf16* pB0 = Bc + (long)(n0 + w * 16 + rr) * 2048 + qq * 8;
    const bf16* pB1 = pB0 + 8 * 2048;

    // swizzled LDS read offsets (elements)
    const int l15 = lane & 15;
    const int q0 = (((lane >> 4) ^ (lane & 7))) * 8;
    const int aoff0 = l15 * 64 + q0, aoff1 = aoff0 ^ 32;
    const int boff0 = ((wc & 1) * 64 + l15) * 64 + q0, boff1 = boff0 ^ 32;
    const int hb = 2 + (wc >> 1);

    f32x4 acc[8][4] = {};
    bf16x8 a_fr[4][2], b_fr[2][2][2];

#define STG(buf, half, P0, P1, e) do { \
    gload_lds16((P0) + (e), &lds[buf][half][w * 1024]); \
    gload_lds16((P1) + (e), &lds[buf][half][w * 1024 + 512]); } while (0)

#define RDA(buf, mb) do { _Pragma("unroll") \
    for (int mm = 0; mm < 4; ++mm) { \
        a_fr[mm][0] = *(const bf16x8*)&lds[buf][wr][aoff0 + (mb + mm) * 1024]; \
        a_fr[mm][1] = *(const bf16x8*)&lds[buf][wr][aoff1 + (mb + mm) * 1024]; } } while (0)

#define RDB(buf, nh) do { _Pragma("unroll") \
    for (int nn = 0; nn < 2; ++nn) { \
        b_fr[nh][nn][0] = *(const bf16x8*)&lds[buf][hb][boff0 + (nh * 2 + nn) * 1024]; \
        b_fr[nh][nn][1] = *(const bf16x8*)&lds[buf][hb][boff1 + (nh * 2 + nn) * 1024]; } } while (0)

#define MFMA16(mb, nh) do { __builtin_amdgcn_s_setprio(1); _Pragma("unroll") \
    for (int mm = 0; mm < 4; ++mm) { _Pragma("unroll") \
        for (int nn = 0; nn < 2; ++nn) { \
            acc[mb + mm][nh * 2 + nn] = __builtin_amdgcn_mfma_f32_16x16x32_bf16(a_fr[mm][0], b_fr[nh][nn][0], acc[mb + mm][nh * 2 + nn], 0, 0, 0); \
            acc[mb + mm][nh * 2 + nn] = __builtin_amdgcn_mfma_f32_16x16x32_bf16(a_fr[mm][1], b_fr[nh][nn][1], acc[mb + mm][nh * 2 + nn], 0, 0, 0); } } \
    __builtin_amdgcn_s_setprio(0); } while (0)

    // prologue: bufA gen0 (A0,A1,B0,B1), bufB gen1 (B0,B1)
    STG(0, 0, pA0, pA1, 0);
    STG(0, 1, pA0, pA1, 262144);
    STG(0, 2, pB0, pB1, 0);
    STG(0, 3, pB0, pB1, 262144);
    STG(1, 2, pB0, pB1, 64);
    STG(1, 3, pB0, pB1, 262144 + 64);
    WAITVM4();
    BARRIER();

#pragma unroll 1
    for (int it = 0; it < 16; ++it) {
        const int kB  = (2 * it + 1) * 64;
        const int kA2 = ((2 * it + 2) & 31) * 64;
        const int kB2 = ((2 * it + 3) & 31) * 64;
        // ph1
        RDA(0, 0); RDB(0, 0);
        STG(1, 0, pA0, pA1, kB);
        BARRIER(); WAITLGKM0();
        MFMA16(0, 0);
        BARRIER();
        // ph2
        RDB(0, 1);
        STG(1, 1, pA0, pA1, 262144 + kB);
        BARRIER(); WAITLGKM0();
        MFMA16(0, 1);
        BARRIER();
        // ph3
        RDA(0, 4);
        STG(0, 2, pB0, pB1, kA2);
        BARRIER(); WAITLGKM0();
        MFMA16(4, 1);
        BARRIER();
        // ph4
        STG(0, 3, pB0, pB1, 262144 + kA2);
        WAITVM4();
        BARRIER();
        MFMA16(4, 0);
        BARRIER();
        // ph5
        RDA(1, 0); RDB(1, 0);
        STG(0, 0, pA0, pA1, kA2);
        BARRIER(); WAITLGKM0();
        MFMA16(0, 0);
        BARRIER();
        // ph6
        RDB(1, 1);
        STG(0, 1, pA0, pA1, 262144 + kA2);
        BARRIER(); WAITLGKM0();
        MFMA16(0, 1);
        BARRIER();
        // ph7
        RDA(1, 4);
        STG(1, 2, pB0, pB1, kB2);
        BARRIER(); WAITLGKM0();
        MFMA16(4, 1);
        BARRIER();
        // ph8
        STG(1, 3, pB0, pB1, 262144 + kB2);
        WAITVM4();
        BARRIER();
        MFMA16(4, 0);
        BARRIER();
    }

    // epilogue
    const int r4 = (lane >> 4) * 4;
    const float* bb = bias + (long)c * bias_cstride;
    const float* cr = corr + (long)c * corr_cstride;
    bf16* oc = out + ((long)c * 4096 + m0 + wr * 128) * N + n0 + wc * 64;
#pragma unroll
    for (int n = 0; n < 4; ++n) {
        const int col = n0 + wc * 64 + n * 16 + l15;
        const float bv = bb[col] + cr[col];
#pragma unroll
        for (int m = 0; m < 8; ++m)
#pragma unroll
            for (int j = 0; j < 4; ++j) {
                const int row = m * 16 + r4 + j;
                oc[(long)row * N + n * 16 + l15] = (bf16)fmaxf(acc[m][n][j] + bv, 0.0f);
            }
    }
#undef STG
#undef RDA
#undef RDB
#undef MFMA16
}

// ---------------- generic 128x128 bf16 GEMM (fp32 out) ----------------
template <int RELU, int HASBIAS>
__global__ __launch_bounds__(256, 2)
void gemm_bf16_kernel(const bf16* __restrict__ A, const bf16* __restrict__ Wt,
                      const float* __restrict__ bias, float* __restrict__ outf,
                      int Kloop, int lda, int ldb,
                      long a_zoff, long w_zoff, long b_cstride,
                      long out_rstride, long out_zoff)
{
    __shared__ __align__(16) bf16 As[128 * 64];
    __shared__ __align__(16) bf16 Bs[128 * 64];

    const int z  = blockIdx.z;
    const int m0 = blockIdx.x * 128;
    const int n0 = blockIdx.y * 128;
    const int t  = threadIdx.x;
    const int lane = t & 63, wave = t >> 6;
    const int wr = wave >> 1, wc = wave & 1;

    const bf16* Ac = A  + (long)z * a_zoff;
    const bf16* W  = Wt + (long)z * w_zoff;
    float* outp = outf + (long)z * out_zoff + (long)m0 * out_rstride + n0;

    const int sr = t >> 3;
    const int sc = (t & 7) * 8;

    f32x4 acc[4][4] = {};

    for (int kt = 0; kt < Kloop / 64; ++kt) {
        const int k0 = kt * 64;
#pragma unroll
        for (int i = 0; i < 4; ++i)
            gload_lds16(Ac + (long)(m0 + i * 32 + sr) * lda + k0 + sc, &As[i * 2048 + wave * 512]);
#pragma unroll
        for (int i = 0; i < 4; ++i)
            gload_lds16(W + (long)(n0 + i * 32 + sr) * ldb + k0 + sc, &Bs[i * 2048 + wave * 512]);
        __syncthreads();

#pragma unroll
        for (int kk = 0; kk < 2; ++kk) {
            bf16x8 af[4], bfr[4];
#pragma unroll
            for (int m = 0; m < 4; ++m)
                af[m] = *(const bf16x8*)&As[(wr * 64 + m * 16 + (lane & 15)) * 64 + kk * 32 + (lane >> 4) * 8];
#pragma unroll
            for (int n = 0; n < 4; ++n)
                bfr[n] = *(const bf16x8*)&Bs[(wc * 64 + n * 16 + (lane & 15)) * 64 + kk * 32 + (lane >> 4) * 8];
#pragma unroll
            for (int m = 0; m < 4; ++m)
#pragma unroll
                for (int n = 0; n < 4; ++n)
                    acc[m][n] = __builtin_amdgcn_mfma_f32_16x16x32_bf16(af[m], bfr[n], acc[m][n], 0, 0, 0);
        }
        __syncthreads();
    }

    const int ci = lane & 15, r4 = (lane >> 4) * 4;
#pragma unroll
    for (int m = 0; m < 4; ++m)
#pragma unroll
        for (int n = 0; n < 4; ++n) {
            const int col = wc * 64 + n * 16 + ci;
            float bv = 0.f;
            if (HASBIAS) bv = bias[(long)z * b_cstride + n0 + col];
#pragma unroll
            for (int j = 0; j < 4; ++j) {
                const int row = wr * 64 + m * 16 + r4 + j;
                float v = acc[m][n][j] + bv;
                if (RELU) v = fmaxf(v, 0.0f);
                outp[(long)row * out_rstride + col] = v;
            }
        }
}

// ---------------- fusion: l2-norm over C, concept prob, bottleneck ----------------
__global__ void fuse_kernel(const float* __restrict__ cm, const float* __restrict__ latent,
                            bf16* __restrict__ bott)
{
    const int wave = threadIdx.x >> 6;
    const int l    = threadIdx.x & 63;
    const int b    = blockIdx.x * 4 + wave;
    const float* cmb  = cm     + (size_t)b * 2048;
    const float* latb = latent + (size_t)b * 2048;

    float sq0 = 0.f, sq1 = 0.f;
#pragma unroll
    for (int c = 0; c < 16; ++c) {
        float v0 = cmb[c * 128 + l], v1 = cmb[c * 128 + 64 + l];
        sq0 += v0 * v0; sq1 += v1 * v1;
    }
    const float rs0 = rsqrtf(fmaxf(sq0, 1e-12f));
    const float rs1 = rsqrtf(fmaxf(sq1, 1e-12f));

#pragma unroll
    for (int c = 0; c < 16; ++c) {
        float cn0 = cmb[c * 128 + l] * rs0;
        float cn1 = cmb[c * 128 + 64 + l] * rs1;
        float part = cn0 * latb[c * 128 + l] + cn1 * latb[c * 128 + 64 + l];
#pragma unroll
        for (int off = 32; off; off >>= 1) part += __shfl_xor(part, off);
        const float p = 1.0f / (1.0f + expf(-part));
        bott[(size_t)b * 1024 + c * 64 + l] = (bf16)(p * cn1 + (1.0f - p) * cn0);
    }
}

// ---------------- final: reduce z partials, relu, logits ----------------
__global__ void head2_kernel(const float* __restrict__ zp, const float* __restrict__ bgh,
                             const float* __restrict__ Wc, const float* __restrict__ bc,
                             float* __restrict__ out)
{
    __shared__ float zrow[128];
    const int b = blockIdx.x;
    const int t = threadIdx.x;
    if (t < 128) {
        float s = bgh[t];
#pragma unroll
        for (int ks = 0; ks < 8; ++ks) s += zp[(size_t)ks * 524288 + (size_t)b * 128 + t];
        zrow[t] = fmaxf(s, 0.0f);
    }
    __syncthreads();
    if (t < 200) {
        float acc = bc[t];
#pragma unroll 8
        for (int k = 0; k < 128; ++k) acc = fmaf(zrow[k], Wc[k * 200 + t], acc);
        out[(size_t)b * 200 + t] = acc;
    }
}

// ---------------- launch ----------------

extern "C" void kernel_launch(void* const* d_in, const int* in_sizes, int n_in,
                              void* d_out, int out_size, void* d_ws, size_t ws_size,
                              hipStream_t stream)
{
    (void)in_sizes; (void)n_in; (void)out_size; (void)ws_size;

    const float* x    = (const float*)d_in[0];
    const float* fp   = (const float*)d_in[1];
    const float* mean = (const float*)d_in[2];
    const float* Wg1  = (const float*)d_in[3];
    const float* bg1  = (const float*)d_in[4];
    const float* Wg2  = (const float*)d_in[5];
    const float* bg2  = (const float*)d_in[6];
    const float* Wf1  = (const float*)d_in[7];
    const float* bf1  = (const float*)d_in[8];
    const float* Wf2  = (const float*)d_in[9];
    const float* bf2  = (const float*)d_in[10];
    const float* Wgh  = (const float*)d_in[11];
    const float* bgh  = (const float*)d_in[12];
    const float* Wc   = (const float*)d_in[13];
    const float* bc   = (const float*)d_in[14];
    float* outp = (float*)d_out;

    char* p = (char*)d_ws;
    size_t off = 0;
    auto alloc = [&](size_t bytes) { void* r = p + off; off += (bytes + 255) & ~(size_t)255; return r; };
    float* gate   = (float*)alloc((size_t)16 * 2048 * 4);
    bf16*  xbf    = (bf16*) alloc((size_t)4096 * 2048 * 2);
    bf16*  Wg1T   = (bf16*) alloc((size_t)16 * 256 * 2048 * 2);
    bf16*  Wf1T   = (bf16*) alloc((size_t)16 * 512 * 2048 * 2);
    bf16*  Wg2T   = (bf16*) alloc((size_t)16 * 128 * 256 * 2);
    bf16*  Wf2T   = (bf16*) alloc((size_t)128 * 512 * 2);
    bf16*  WghT   = (bf16*) alloc((size_t)128 * 1024 * 2);
    float* corr_g = (float*)alloc((size_t)16 * 256 * 4);
    float* corr_f = (float*)alloc((size_t)16 * 512 * 4);
    bf16*  h      = (bf16*) alloc((size_t)16 * 4096 * 256 * 2);
    bf16*  hf     = (bf16*) alloc((size_t)16 * 4096 * 512 * 2);
    float* cm     = (float*)alloc((size_t)4096 * 2048 * 4);
    float* lat    = (float*)alloc((size_t)4096 * 2048 * 4);
    bf16*  bott   = (bf16*) alloc((size_t)4096 * 1024 * 2);
    float* zp     = (float*)alloc((size_t)8 * 4096 * 128 * 4);

    sigmoid_kernel<<<128, 256, 0, stream>>>(fp, gate, 16 * 2048);
    cvt_x<<<4096, 256, 0, stream>>>(x, xbf);
    hipMemsetAsync(corr_g, 0, (size_t)16 * 256 * 4, stream);
    hipMemsetAsync(corr_f, 0, (size_t)16 * 512 * 4, stream);

    prep_w<1, 1><<<dim3(8, 64, 16), 256, 0, stream>>>(
        Wg1, Wg1T, 2048, 256, (long)2048 * 256, (long)2048 * 256, gate, mean, corr_g);
    prep_w<1, 16><<<dim3(16, 64, 1), 256, 0, stream>>>(
        Wf1, Wf1T, 2048, 512, 0, (long)2048 * 512, gate, mean, corr_f);
    prep_w<0, 1><<<dim3(4, 8, 16), 256, 0, stream>>>(
        Wg2, Wg2T, 256, 128, (long)256 * 128, (long)256 * 128, nullptr, nullptr, nullptr);
    prep_w<0, 1><<<dim3(4, 16, 1), 256, 0, stream>>>(
        Wf2, Wf2T, 512, 128, 0, 0, nullptr, nullptr, nullptr);
    prep_w<0, 1><<<dim3(4, 32, 1), 256, 0, stream>>>(
        Wgh, WghT, 1024, 128, 0, 0, nullptr, nullptr, nullptr);

    // h = relu(x @ (g.Wg1) + bg1 + corr_g)   [c][4096][256]
    gemm256<<<dim3(16, 1, 16), 512, 0, stream>>>(
        xbf, Wg1T, bg1, corr_g, h, 256, (long)256 * 2048, 256, 256);
    // hf = relu(x @ (g.Wf1) + bf1 + corr_f)  [c][4096][512]
    gemm256<<<dim3(16, 2, 16), 512, 0, stream>>>(
        xbf, Wf1T, bf1, corr_f, hf, 512, (long)512 * 2048, 0, 512);

    // cm[b][c][l] = h[c] @ Wg2[c]^T + bg2[c]
    gemm_bf16_kernel<0, 1><<<dim3(32, 1, 16), 256, 0, stream>>>(
        h, Wg2T, bg2, cm, 256, 256, 256, (long)4096 * 256, (long)128 * 256, 128, 2048, 128);
    // lat[b][c][l] = hf[c] @ Wf2^T + bf2
    gemm_bf16_kernel<0, 1><<<dim3(32, 1, 16), 256, 0, stream>>>(
        hf, Wf2T, bf2, lat, 512, 512, 512, (long)4096 * 512, 0, 0, 2048, 128);

    fuse_kernel<<<1024, 256, 0, stream>>>(cm, lat, bott);

    // z partials: zp[ks][b][t] = bott[:, ks*128:(ks+1)*128] @ WghT[:, ks*128:(ks+1)*128]^T
    gemm_bf16_kernel<0, 0><<<dim3(32, 1, 8), 256, 0, stream>>>(
        bott, WghT, nullptr, zp, 128, 1024, 1024, 128, 128, 0, 128, (long)4096 * 128);

    head2_kernel<<<4096, 256, 0, stream>>>(zp, bgh, Wc, bc, outp);
}

// Round 3
// 400.148 us; speedup vs baseline: 1.0711x; 1.0130x over previous
//
#include <hip/hip_runtime.h>
#include <hip/hip_bf16.h>

typedef __bf16 bf16;
typedef __attribute__((ext_vector_type(8))) __bf16 bf16x8;
typedef __attribute__((ext_vector_type(4))) float f32x4;

__device__ __forceinline__ void gload_lds16(const void* g, void* l) {
    __builtin_amdgcn_global_load_lds(
        (const __attribute__((address_space(1))) unsigned int*)g,
        (__attribute__((address_space(3))) unsigned int*)l, 16, 0, 0);
}

#define BARRIER()   asm volatile("s_barrier" ::: "memory")
#define WAITLGKM0() asm volatile("s_waitcnt lgkmcnt(0)" ::: "memory")
#define WAITLGKM8() asm volatile("s_waitcnt lgkmcnt(8)" ::: "memory")
#define WAITVM4()   asm volatile("s_waitcnt vmcnt(4)" ::: "memory")

// ---------------- prep kernels ----------------

__global__ void cvt_x(const float* __restrict__ in, bf16* __restrict__ out) {
    const long i = ((long)blockIdx.x * 256 + threadIdx.x) * 8;
    float4 v0 = *(const float4*)(in + i);
    float4 v1 = *(const float4*)(in + i + 4);
    bf16x8 o;
    o[0]=(bf16)v0.x; o[1]=(bf16)v0.y; o[2]=(bf16)v0.z; o[3]=(bf16)v0.w;
    o[4]=(bf16)v1.x; o[5]=(bf16)v1.y; o[6]=(bf16)v1.z; o[7]=(bf16)v1.w;
    *(bf16x8*)(out + i) = o;
}

// in: [z][R][S] fp32 -> out[batch]: [S][R] bf16 (transposed), scaled by sigmoid(fp[batch][r]);
// corr[batch][s] += sum_r (1-g)*mean[r]*W[r][s]  (atomic).
template <int SCALED, int NB>
__global__ void prep_w(const float* __restrict__ in, bf16* __restrict__ out,
                       int R, int S, long in_bstride, long out_bstride,
                       const float* __restrict__ fp, const float* __restrict__ mean,
                       float* __restrict__ corr)
{
    __shared__ float tile[32][33];
    const int s0 = blockIdx.x * 32, r0 = blockIdx.y * 32;
    const int tx = threadIdx.x & 31, ty = threadIdx.x >> 5;
    const float* inb = in + (long)blockIdx.z * in_bstride;
#pragma unroll
    for (int i = 0; i < 32; i += 8)
        tile[ty + i][tx] = inb[(long)(r0 + ty + i) * S + s0 + tx];
    __syncthreads();
    const float mv = SCALED ? mean[r0 + tx] : 0.f;
#pragma unroll 1
    for (int b2 = 0; b2 < NB; ++b2) {
        const int batch = blockIdx.z * NB + b2;
        bf16* outb = out + (long)batch * out_bstride;
        float gv = 1.f, gmv = 0.f;
        if (SCALED) {
            gv = 1.f / (1.f + expf(-fp[(long)batch * R + r0 + tx]));
            gmv = (1.f - gv) * mv;
        }
#pragma unroll
        for (int i = 0; i < 32; i += 8) {
            const float wv = tile[tx][ty + i];
            outb[(long)(s0 + ty + i) * R + r0 + tx] = (bf16)(gv * wv);
            if (SCALED) {
                float v = gmv * wv;
#pragma unroll
                for (int off = 16; off; off >>= 1) v += __shfl_xor(v, off);
                if (tx == 0) atomicAdd(&corr[(long)batch * S + s0 + ty + i], v);
            }
        }
    }
}

// ---------------- 256x256 8-phase bf16 GEMM (K=2048), merged h+hf ----------------
// Wall: [c][768][2048] bf16 (rows 0-255 = g.Wg1, 256-767 = g.Wf1).
// block ny==0 -> h[c][4096][256]; ny in {1,2} -> hf[c][4096][512] cols (ny-1)*256..
__global__ __launch_bounds__(512, 2)
void gemm256(const bf16* __restrict__ A, const bf16* __restrict__ Wall,
             const float* __restrict__ bg1, const float* __restrict__ corr_g,
             const float* __restrict__ bf1, const float* __restrict__ corr_f,
             bf16* __restrict__ h_out, bf16* __restrict__ hf_out)
{
    __shared__ __align__(16) bf16 lds[2][4][8192];  // [buf][A0,A1,B0,B1][128*64]

    // bijective XCD swizzle, c-major: XCD k owns swz in [k*96,(k+1)*96) -> c={2k,2k+1}
    const int bid = blockIdx.x;                 // grid = 768
    const int swz = (bid & 7) * 96 + (bid >> 3);
    const int c   = swz / 48;
    const int rem = swz % 48;
    const int ny  = rem / 16;
    const int m0  = (rem % 16) * 256;

    const int t = threadIdx.x, lane = t & 63, w = t >> 6;
    const int wr = w >> 2, wc = w & 3;
    const bf16* Bc = Wall + (long)c * 768 * 2048;

    // staging: lane's 16B chunk -> swizzled global source (q = (lane&7)^(lane>>3))
    const int rr = lane >> 3;
    const int qq = (lane & 7) ^ rr;
    const bf16* pA0 = A  + (long)(m0 + w * 16 + rr) * 2048 + qq * 8;
    const bf16* pA1 = pA0 + 8 * 2048;
    const bf16* pB0 = Bc + (long)(ny * 256 + w * 16 + rr) * 2048 + qq * 8;
    const bf16* pB1 = pB0 + 8 * 2048;

    // swizzled LDS read offsets (elements)
    const int l15 = lane & 15;
    const int q0 = (((lane >> 4) ^ (lane & 7))) * 8;
    const int aoff0 = l15 * 64 + q0, aoff1 = aoff0 ^ 32;
    const int boff0 = ((wc & 1) * 64 + l15) * 64 + q0, boff1 = boff0 ^ 32;
    const int hb = 2 + (wc >> 1);

    f32x4 acc[8][4] = {};
    bf16x8 a_fr[4][2], b_fr[2][2][2];

#define STG(buf, half, P0, P1, e) do { \
    gload_lds16((P0) + (e), &lds[buf][half][w * 1024]); \
    gload_lds16((P1) + (e), &lds[buf][half][w * 1024 + 512]); } while (0)

#define RDA(buf, mb) do { _Pragma("unroll") \
    for (int mm = 0; mm < 4; ++mm) { \
        a_fr[mm][0] = *(const bf16x8*)&lds[buf][wr][aoff0 + (mb + mm) * 1024]; \
        a_fr[mm][1] = *(const bf16x8*)&lds[buf][wr][aoff1 + (mb + mm) * 1024]; } } while (0)

#define RDB(buf, nh) do { _Pragma("unroll") \
    for (int nn = 0; nn < 2; ++nn) { \
        b_fr[nh][nn][0] = *(const bf16x8*)&lds[buf][hb][boff0 + (nh * 2 + nn) * 1024]; \
        b_fr[nh][nn][1] = *(const bf16x8*)&lds[buf][hb][boff1 + (nh * 2 + nn) * 1024]; } } while (0)

// k-outer: dependent writes to the same acc are 8 MFMAs apart
#define MFMA16(mb, nh) do { __builtin_amdgcn_s_setprio(1); _Pragma("unroll") \
    for (int kk = 0; kk < 2; ++kk) { _Pragma("unroll") \
      for (int mm = 0; mm < 4; ++mm) { _Pragma("unroll") \
        for (int nn = 0; nn < 2; ++nn) { \
            acc[mb + mm][nh * 2 + nn] = __builtin_amdgcn_mfma_f32_16x16x32_bf16( \
                a_fr[mm][kk], b_fr[nh][nn][kk], acc[mb + mm][nh * 2 + nn], 0, 0, 0); } } } \
    __builtin_amdgcn_s_setprio(0); } while (0)

    // prologue: buf0 gen0 (A0,A1,B0,B1), buf1 gen1 (B0,B1)
    STG(0, 0, pA0, pA1, 0);
    STG(0, 1, pA0, pA1, 262144);
    STG(0, 2, pB0, pB1, 0);
    STG(0, 3, pB0, pB1, 262144);
    STG(1, 2, pB0, pB1, 64);
    STG(1, 3, pB0, pB1, 262144 + 64);
    WAITVM4();
    BARRIER();

#pragma unroll 1
    for (int it = 0; it < 16; ++it) {
        const int kB  = (2 * it + 1) * 64;
        const int kA2 = ((2 * it + 2) & 31) * 64;
        const int kB2 = ((2 * it + 3) & 31) * 64;
        // ph1
        RDA(0, 0); RDB(0, 0);
        STG(1, 0, pA0, pA1, kB);
        WAITLGKM8();
        BARRIER(); WAITLGKM0();
        MFMA16(0, 0);
        BARRIER();
        // ph2
        RDB(0, 1);
        STG(1, 1, pA0, pA1, 262144 + kB);
        BARRIER(); WAITLGKM0();
        MFMA16(0, 1);
        BARRIER();
        // ph3
        RDA(0, 4);
        STG(0, 2, pB0, pB1, kA2);
        BARRIER(); WAITLGKM0();
        MFMA16(4, 1);
        BARRIER();
        // ph4
        STG(0, 3, pB0, pB1, 262144 + kA2);
        WAITVM4();
        BARRIER();
        MFMA16(4, 0);
        BARRIER();
        // ph5
        RDA(1, 0); RDB(1, 0);
        STG(0, 0, pA0, pA1, kA2);
        WAITLGKM8();
        BARRIER(); WAITLGKM0();
        MFMA16(0, 0);
        BARRIER();
        // ph6
        RDB(1, 1);
        STG(0, 1, pA0, pA1, 262144 + kA2);
        BARRIER(); WAITLGKM0();
        MFMA16(0, 1);
        BARRIER();
        // ph7
        RDA(1, 4);
        STG(1, 2, pB0, pB1, kB2);
        BARRIER(); WAITLGKM0();
        MFMA16(4, 1);
        BARRIER();
        // ph8
        STG(1, 3, pB0, pB1, 262144 + kB2);
        WAITVM4();
        BARRIER();
        MFMA16(4, 0);
        BARRIER();
    }

    // epilogue
    const int r4 = (lane >> 4) * 4;
    const int isH = (ny == 0);
    const int N = isH ? 256 : 512;
    bf16* oc = (isH ? h_out + ((long)c * 4096 + m0 + wr * 128) * 256
                    : hf_out + ((long)c * 4096 + m0 + wr * 128) * 512 + (ny - 1) * 256)
               + wc * 64;
#pragma unroll
    for (int n = 0; n < 4; ++n) {
        const int cl = wc * 64 + n * 16 + l15;           // col within this block's 256
        float bv;
        if (isH) bv = bg1[c * 256 + cl] + corr_g[c * 256 + cl];
        else {
            const int cf = (ny - 1) * 256 + cl;
            bv = bf1[cf] + corr_f[c * 512 + cf];
        }
#pragma unroll
        for (int m = 0; m < 8; ++m)
#pragma unroll
            for (int j = 0; j < 4; ++j) {
                const int row = m * 16 + r4 + j;
                oc[(long)row * N + n * 16 + l15] = (bf16)fmaxf(acc[m][n][j] + bv, 0.0f);
            }
    }
#undef STG
#undef RDA
#undef RDB
#undef MFMA16
}

// ---------------- generic 128x128 bf16 GEMM (fp32 out) ----------------
template <int RELU, int HASBIAS>
__global__ __launch_bounds__(256, 2)
void gemm_bf16_kernel(const bf16* __restrict__ A, const bf16* __restrict__ Wt,
                      const float* __restrict__ bias, float* __restrict__ outf,
                      int Kloop, int lda, int ldb,
                      long a_zoff, long w_zoff, long b_cstride,
                      long out_rstride, long out_zoff)
{
    __shared__ __align__(16) bf16 As[128 * 64];
    __shared__ __align__(16) bf16 Bs[128 * 64];

    const int z  = blockIdx.z;
    const int m0 = blockIdx.x * 128;
    const int n0 = blockIdx.y * 128;
    const int t  = threadIdx.x;
    const int lane = t & 63, wave = t >> 6;
    const int wr = wave >> 1, wc = wave & 1;

    const bf16* Ac = A  + (long)z * a_zoff;
    const bf16* W  = Wt + (long)z * w_zoff;
    float* outp = outf + (long)z * out_zoff + (long)m0 * out_rstride + n0;

    const int sr = t >> 3;
    const int sc = (t & 7) * 8;

    f32x4 acc[4][4] = {};

    for (int kt = 0; kt < Kloop / 64; ++kt) {
        const int k0 = kt * 64;
#pragma unroll
        for (int i = 0; i < 4; ++i)
            gload_lds16(Ac + (long)(m0 + i * 32 + sr) * lda + k0 + sc, &As[i * 2048 + wave * 512]);
#pragma unroll
        for (int i = 0; i < 4; ++i)
            gload_lds16(W + (long)(n0 + i * 32 + sr) * ldb + k0 + sc, &Bs[i * 2048 + wave * 512]);
        __syncthreads();

#pragma unroll
        for (int kk = 0; kk < 2; ++kk) {
            bf16x8 af[4], bfr[4];
#pragma unroll
            for (int m = 0; m < 4; ++m)
                af[m] = *(const bf16x8*)&As[(wr * 64 + m * 16 + (lane & 15)) * 64 + kk * 32 + (lane >> 4) * 8];
#pragma unroll
            for (int n = 0; n < 4; ++n)
                bfr[n] = *(const bf16x8*)&Bs[(wc * 64 + n * 16 + (lane & 15)) * 64 + kk * 32 + (lane >> 4) * 8];
#pragma unroll
            for (int m = 0; m < 4; ++m)
#pragma unroll
                for (int n = 0; n < 4; ++n)
                    acc[m][n] = __builtin_amdgcn_mfma_f32_16x16x32_bf16(af[m], bfr[n], acc[m][n], 0, 0, 0);
        }
        __syncthreads();
    }

    const int ci = lane & 15, r4 = (lane >> 4) * 4;
#pragma unroll
    for (int m = 0; m < 4; ++m)
#pragma unroll
        for (int n = 0; n < 4; ++n) {
            const int col = wc * 64 + n * 16 + ci;
            float bv = 0.f;
            if (HASBIAS) bv = bias[(long)z * b_cstride + n0 + col];
#pragma unroll
            for (int j = 0; j < 4; ++j) {
                const int row = wr * 64 + m * 16 + r4 + j;
                float v = acc[m][n][j] + bv;
                if (RELU) v = fmaxf(v, 0.0f);
                outp[(long)row * out_rstride + col] = v;
            }
        }
}

// ---------------- fusion: l2-norm over C, concept prob, bottleneck ----------------
__global__ void fuse_kernel(const float* __restrict__ cm, const float* __restrict__ latent,
                            bf16* __restrict__ bott)
{
    const int wave = threadIdx.x >> 6;
    const int l    = threadIdx.x & 63;
    const int b    = blockIdx.x * 4 + wave;
    const float* cmb  = cm     + (size_t)b * 2048;
    const float* latb = latent + (size_t)b * 2048;

    float sq0 = 0.f, sq1 = 0.f;
#pragma unroll
    for (int c = 0; c < 16; ++c) {
        float v0 = cmb[c * 128 + l], v1 = cmb[c * 128 + 64 + l];
        sq0 += v0 * v0; sq1 += v1 * v1;
    }
    const float rs0 = rsqrtf(fmaxf(sq0, 1e-12f));
    const float rs1 = rsqrtf(fmaxf(sq1, 1e-12f));

#pragma unroll
    for (int c = 0; c < 16; ++c) {
        float cn0 = cmb[c * 128 + l] * rs0;
        float cn1 = cmb[c * 128 + 64 + l] * rs1;
        float part = cn0 * latb[c * 128 + l] + cn1 * latb[c * 128 + 64 + l];
#pragma unroll
        for (int off = 32; off; off >>= 1) part += __shfl_xor(part, off);
        const float p = 1.0f / (1.0f + expf(-part));
        bott[(size_t)b * 1024 + c * 64 + l] = (bf16)(p * cn1 + (1.0f - p) * cn0);
    }
}

// ---------------- final: reduce z partials, relu, logits ----------------
__global__ void head2_kernel(const float* __restrict__ zp, const float* __restrict__ bgh,
                             const float* __restrict__ Wc, const float* __restrict__ bc,
                             float* __restrict__ out)
{
    __shared__ float zrow[128];
    const int b = blockIdx.x;
    const int t = threadIdx.x;
    if (t < 128) {
        float s = bgh[t];
#pragma unroll
        for (int ks = 0; ks < 8; ++ks) s += zp[(size_t)ks * 524288 + (size_t)b * 128 + t];
        zrow[t] = fmaxf(s, 0.0f);
    }
    __syncthreads();
    if (t < 200) {
        float acc = bc[t];
#pragma unroll 8
        for (int k = 0; k < 128; ++k) acc = fmaf(zrow[k], Wc[k * 200 + t], acc);
        out[(size_t)b * 200 + t] = acc;
    }
}

// ---------------- launch ----------------

extern "C" void kernel_launch(void* const* d_in, const int* in_sizes, int n_in,
                              void* d_out, int out_size, void* d_ws, size_t ws_size,
                              hipStream_t stream)
{
    (void)in_sizes; (void)n_in; (void)out_size; (void)ws_size;

    const float* x    = (const float*)d_in[0];
    const float* fp   = (const float*)d_in[1];
    const float* mean = (const float*)d_in[2];
    const float* Wg1  = (const float*)d_in[3];
    const float* bg1  = (const float*)d_in[4];
    const float* Wg2  = (const float*)d_in[5];
    const float* bg2  = (const float*)d_in[6];
    const float* Wf1  = (const float*)d_in[7];
    const float* bf1  = (const float*)d_in[8];
    const float* Wf2  = (const float*)d_in[9];
    const float* bf2  = (const float*)d_in[10];
    const float* Wgh  = (const float*)d_in[11];
    const float* bgh  = (const float*)d_in[12];
    const float* Wc   = (const float*)d_in[13];
    const float* bc   = (const float*)d_in[14];
    float* outp = (float*)d_out;

    char* p = (char*)d_ws;
    size_t off = 0;
    auto alloc = [&](size_t bytes) { void* r = p + off; off += (bytes + 255) & ~(size_t)255; return r; };
    bf16*  xbf    = (bf16*) alloc((size_t)4096 * 2048 * 2);
    bf16*  Wall   = (bf16*) alloc((size_t)16 * 768 * 2048 * 2);
    bf16*  Wg2T   = (bf16*) alloc((size_t)16 * 128 * 256 * 2);
    bf16*  Wf2T   = (bf16*) alloc((size_t)128 * 512 * 2);
    bf16*  WghT   = (bf16*) alloc((size_t)128 * 1024 * 2);
    float* corr_g = (float*)alloc((size_t)16 * 256 * 4);   // 16 KB
    float* corr_f = (float*)alloc((size_t)16 * 512 * 4);   // 32 KB (adjacent to corr_g)
    bf16*  h      = (bf16*) alloc((size_t)16 * 4096 * 256 * 2);
    bf16*  hf     = (bf16*) alloc((size_t)16 * 4096 * 512 * 2);
    float* cm     = (float*)alloc((size_t)4096 * 2048 * 4);
    float* lat    = (float*)alloc((size_t)4096 * 2048 * 4);
    bf16*  bott   = (bf16*) alloc((size_t)4096 * 1024 * 2);
    float* zp     = (float*)alloc((size_t)8 * 4096 * 128 * 4);

    hipMemsetAsync(corr_g, 0, (size_t)(16 * 256 + 16 * 512) * 4, stream);
    cvt_x<<<4096, 256, 0, stream>>>(x, xbf);

    // Wall rows 0-255 <- sigmoid(fp[c]) * Wg1[c];  rows 256-767 <- sigmoid(fp[c]) * Wf1
    prep_w<1, 1><<<dim3(8, 64, 16), 256, 0, stream>>>(
        Wg1, Wall, 2048, 256, (long)2048 * 256, (long)768 * 2048, fp, mean, corr_g);
    prep_w<1, 16><<<dim3(16, 64, 1), 256, 0, stream>>>(
        Wf1, Wall + (size_t)256 * 2048, 2048, 512, 0, (long)768 * 2048, fp, mean, corr_f);
    prep_w<0, 1><<<dim3(4, 8, 16), 256, 0, stream>>>(
        Wg2, Wg2T, 256, 128, (long)256 * 128, (long)256 * 128, nullptr, nullptr, nullptr);
    prep_w<0, 1><<<dim3(4, 16, 1), 256, 0, stream>>>(
        Wf2, Wf2T, 512, 128, 0, 0, nullptr, nullptr, nullptr);
    prep_w<0, 1><<<dim3(4, 32, 1), 256, 0, stream>>>(
        Wgh, WghT, 1024, 128, 0, 0, nullptr, nullptr, nullptr);

    // h = relu(x @ (g.Wg1) + bg1 + corr_g); hf = relu(x @ (g.Wf1) + bf1 + corr_f)
    gemm256<<<768, 512, 0, stream>>>(xbf, Wall, bg1, corr_g, bf1, corr_f, h, hf);

    // cm[b][c][l] = h[c] @ Wg2[c]^T + bg2[c]
    gemm_bf16_kernel<0, 1><<<dim3(32, 1, 16), 256, 0, stream>>>(
        h, Wg2T, bg2, cm, 256, 256, 256, (long)4096 * 256, (long)128 * 256, 128, 2048, 128);
    // lat[b][c][l] = hf[c] @ Wf2^T + bf2
    gemm_bf16_kernel<0, 1><<<dim3(32, 1, 16), 256, 0, stream>>>(
        hf, Wf2T, bf2, lat, 512, 512, 512, (long)4096 * 512, 0, 0, 2048, 128);

    fuse_kernel<<<1024, 256, 0, stream>>>(cm, lat, bott);

    // z partials: zp[ks][b][t]
    gemm_bf16_kernel<0, 0><<<dim3(32, 1, 8), 256, 0, stream>>>(
        bott, WghT, nullptr, zp, 128, 1024, 1024, 128, 128, 0, 128, (long)4096 * 128);

    head2_kernel<<<4096, 256, 0, stream>>>(zp, bgh, Wc, bc, outp);
}

// Round 4
// 393.315 us; speedup vs baseline: 1.0897x; 1.0174x over previous
//
#include <hip/hip_runtime.h>
#include <hip/hip_bf16.h>

typedef __bf16 bf16;
typedef __attribute__((ext_vector_type(8))) __bf16 bf16x8;
typedef __attribute__((ext_vector_type(4))) float f32x4;

__device__ __forceinline__ void gload_lds16(const void* g, void* l) {
    __builtin_amdgcn_global_load_lds(
        (const __attribute__((address_space(1))) unsigned int*)g,
        (__attribute__((address_space(3))) unsigned int*)l, 16, 0, 0);
}

#define BARRIER()   asm volatile("s_barrier" ::: "memory")
#define WAITVM4()   asm volatile("s_waitcnt vmcnt(4)" ::: "memory")
#define SCHED0()    __builtin_amdgcn_sched_barrier(0)

// ---------------- prep kernels ----------------

__global__ void cvt_x(const float* __restrict__ in, bf16* __restrict__ out) {
    const long i = ((long)blockIdx.x * 256 + threadIdx.x) * 8;
    float4 v0 = *(const float4*)(in + i);
    float4 v1 = *(const float4*)(in + i + 4);
    bf16x8 o;
    o[0]=(bf16)v0.x; o[1]=(bf16)v0.y; o[2]=(bf16)v0.z; o[3]=(bf16)v0.w;
    o[4]=(bf16)v1.x; o[5]=(bf16)v1.y; o[6]=(bf16)v1.z; o[7]=(bf16)v1.w;
    *(bf16x8*)(out + i) = o;
}

// in: [z][R][S] fp32 -> out[batch]: [S][R] bf16 (transposed), scaled by sigmoid(fp[batch][r]);
// corr[batch][s] += sum_r (1-g)*mean[r]*W[r][s]  (atomic).
template <int SCALED, int NB>
__global__ void prep_w(const float* __restrict__ in, bf16* __restrict__ out,
                       int R, int S, long in_bstride, long out_bstride,
                       const float* __restrict__ fp, const float* __restrict__ mean,
                       float* __restrict__ corr)
{
    __shared__ float tile[32][33];
    const int s0 = blockIdx.x * 32, r0 = blockIdx.y * 32;
    const int tx = threadIdx.x & 31, ty = threadIdx.x >> 5;
    const float* inb = in + (long)blockIdx.z * in_bstride;
#pragma unroll
    for (int i = 0; i < 32; i += 8)
        tile[ty + i][tx] = inb[(long)(r0 + ty + i) * S + s0 + tx];
    __syncthreads();
    const float mv = SCALED ? mean[r0 + tx] : 0.f;
#pragma unroll 1
    for (int b2 = 0; b2 < NB; ++b2) {
        const int batch = blockIdx.z * NB + b2;
        bf16* outb = out + (long)batch * out_bstride;
        float gv = 1.f, gmv = 0.f;
        if (SCALED) {
            gv = 1.f / (1.f + expf(-fp[(long)batch * R + r0 + tx]));
            gmv = (1.f - gv) * mv;
        }
#pragma unroll
        for (int i = 0; i < 32; i += 8) {
            const float wv = tile[tx][ty + i];
            outb[(long)(s0 + ty + i) * R + r0 + tx] = (bf16)(gv * wv);
            if (SCALED) {
                float v = gmv * wv;
#pragma unroll
                for (int off = 16; off; off >>= 1) v += __shfl_xor(v, off);
                if (tx == 0) atomicAdd(&corr[(long)batch * S + s0 + ty + i], v);
            }
        }
    }
}

// ---------------- 256x256 8-phase bf16 GEMM (K=2048), merged h+hf ----------------
// Register-pipelined: each phase's MFMA consumes fragments ds_read one phase earlier.
__global__ __launch_bounds__(512, 2)
void gemm256(const bf16* __restrict__ A, const bf16* __restrict__ Wall,
             const float* __restrict__ bg1, const float* __restrict__ corr_g,
             const float* __restrict__ bf1, const float* __restrict__ corr_f,
             bf16* __restrict__ h_out, bf16* __restrict__ hf_out)
{
    __shared__ __align__(16) bf16 lds[2][4][8192];  // [buf][A0,A1,B0,B1][128*64]

    // bijective XCD swizzle, c-major
    const int bid = blockIdx.x;                 // grid = 768
    const int swz = (bid & 7) * 96 + (bid >> 3);
    const int c   = swz / 48;
    const int rem = swz % 48;
    const int ny  = rem / 16;
    const int m0  = (rem % 16) * 256;

    const int t = threadIdx.x, lane = t & 63, w = t >> 6;
    const int wr = w >> 2, wc = w & 3;
    const bf16* Bc = Wall + (long)c * 768 * 2048;

    // staging: lane's 16B chunk -> swizzled global source (q = (lane&7)^(lane>>3))
    const int rr = lane >> 3;
    const int qq = (lane & 7) ^ rr;
    const bf16* pA0 = A  + (long)(m0 + w * 16 + rr) * 2048 + qq * 8;
    const bf16* pA1 = pA0 + 8 * 2048;
    const bf16* pB0 = Bc + (long)(ny * 256 + w * 16 + rr) * 2048 + qq * 8;
    const bf16* pB1 = pB0 + 8 * 2048;

    // swizzled LDS read offsets (elements)
    const int l15 = lane & 15;
    const int q0 = (((lane >> 4) ^ (lane & 7))) * 8;
    const int aoff0 = l15 * 64 + q0, aoff1 = aoff0 ^ 32;
    const int boff0 = ((wc & 1) * 64 + l15) * 64 + q0, boff1 = boff0 ^ 32;
    const int hb = 2 + (wc >> 1);

    f32x4 acc[8][4] = {};
    bf16x8 Ax[4][2], Ay[4][2], Bx[2][2], By[2][2];

#define STG(buf, half, P0, P1, e) do { \
    gload_lds16((P0) + (e), &lds[buf][half][w * 1024]); \
    gload_lds16((P1) + (e), &lds[buf][half][w * 1024 + 512]); } while (0)

#define RDA(dst, buf, mb) do { _Pragma("unroll") \
    for (int mm = 0; mm < 4; ++mm) { \
        dst[mm][0] = *(const bf16x8*)&lds[buf][wr][aoff0 + (mb + mm) * 1024]; \
        dst[mm][1] = *(const bf16x8*)&lds[buf][wr][aoff1 + (mb + mm) * 1024]; } } while (0)

#define RDB(dst, buf, nh) do { _Pragma("unroll") \
    for (int nn = 0; nn < 2; ++nn) { \
        dst[nn][0] = *(const bf16x8*)&lds[buf][hb][boff0 + (nh * 2 + nn) * 1024]; \
        dst[nn][1] = *(const bf16x8*)&lds[buf][hb][boff1 + (nh * 2 + nn) * 1024]; } } while (0)

// k-outer: dependent writes to the same acc are 8 MFMAs apart
#define MFMA16(mb, Af, Bf, nh) do { __builtin_amdgcn_s_setprio(1); _Pragma("unroll") \
    for (int kk = 0; kk < 2; ++kk) { _Pragma("unroll") \
      for (int mm = 0; mm < 4; ++mm) { _Pragma("unroll") \
        for (int nn = 0; nn < 2; ++nn) { \
            acc[mb + mm][nh * 2 + nn] = __builtin_amdgcn_mfma_f32_16x16x32_bf16( \
                Af[mm][kk], Bf[nn][kk], acc[mb + mm][nh * 2 + nn], 0, 0, 0); } } } \
    __builtin_amdgcn_s_setprio(0); } while (0)

    // prologue: buf0 all 4 half-tiles (k-tile 0), buf1 B0,B1 (k-tile 1)
    STG(0, 0, pA0, pA1, 0);
    STG(0, 1, pA0, pA1, 262144);
    STG(0, 2, pB0, pB1, 0);
    STG(0, 3, pB0, pB1, 262144);
    STG(1, 2, pB0, pB1, 64);
    STG(1, 3, pB0, pB1, 262144 + 64);
    WAITVM4();
    BARRIER();
    RDA(Ax, 0, 0); RDB(Bx, 0, 0);   // fragments for ph1

#pragma unroll 1
    for (int it = 0; it < 16; ++it) {
        const int kB  = (2 * it + 1) * 64;
        const int kA2 = ((2 * it + 2) & 31) * 64;
        const int kB2 = ((2 * it + 3) & 31) * 64;
        // ph1: compute (mb0, nh0) on buf0; read By(buf0,nh1) for ph2
        STG(1, 0, pA0, pA1, kB);
        BARRIER();
        RDB(By, 0, 1);
        SCHED0();
        MFMA16(0, Ax, Bx, 0);
        BARRIER();
        // ph2: compute (mb0, nh1); read Ay(buf0,mb4) for ph3/ph4
        STG(1, 1, pA0, pA1, 262144 + kB);
        BARRIER();
        RDA(Ay, 0, 4);
        SCHED0();
        MFMA16(0, Ax, By, 1);
        BARRIER();
        // ph3: compute (mb4, nh1)
        STG(0, 2, pB0, pB1, kA2);
        BARRIER();
        MFMA16(4, Ay, By, 1);
        BARRIER();
        // ph4: compute (mb4, nh0); read Ax(buf1) pre-MFMA, Bx(buf1) post-MFMA (reg WAR)
        STG(0, 3, pB0, pB1, 262144 + kA2);
        WAITVM4();
        BARRIER();
        RDA(Ax, 1, 0);
        SCHED0();
        MFMA16(4, Ay, Bx, 0);
        RDB(Bx, 1, 0);
        BARRIER();
        // ph5: buf1 k-tile: (mb0, nh0); read By(buf1,nh1)
        STG(0, 0, pA0, pA1, kA2);
        BARRIER();
        RDB(By, 1, 1);
        SCHED0();
        MFMA16(0, Ax, Bx, 0);
        BARRIER();
        // ph6: (mb0, nh1); read Ay(buf1,mb4)
        STG(0, 1, pA0, pA1, 262144 + kA2);
        BARRIER();
        RDA(Ay, 1, 4);
        SCHED0();
        MFMA16(0, Ax, By, 1);
        BARRIER();
        // ph7: (mb4, nh1)
        STG(1, 2, pB0, pB1, kB2);
        BARRIER();
        MFMA16(4, Ay, By, 1);
        BARRIER();
        // ph8: (mb4, nh0); read Ax(buf0 next) pre-MFMA, Bx(buf0 next) post-MFMA
        STG(1, 3, pB0, pB1, 262144 + kB2);
        WAITVM4();
        BARRIER();
        RDA(Ax, 0, 0);
        SCHED0();
        MFMA16(4, Ay, Bx, 0);
        RDB(Bx, 0, 0);
        BARRIER();
    }

    // epilogue
    const int r4 = (lane >> 4) * 4;
    const int isH = (ny == 0);
    const int N = isH ? 256 : 512;
    bf16* oc = (isH ? h_out + ((long)c * 4096 + m0 + wr * 128) * 256
                    : hf_out + ((long)c * 4096 + m0 + wr * 128) * 512 + (ny - 1) * 256)
               + wc * 64;
#pragma unroll
    for (int n = 0; n < 4; ++n) {
        const int cl = wc * 64 + n * 16 + l15;
        float bv;
        if (isH) bv = bg1[c * 256 + cl] + corr_g[c * 256 + cl];
        else {
            const int cf = (ny - 1) * 256 + cl;
            bv = bf1[cf] + corr_f[c * 512 + cf];
        }
#pragma unroll
        for (int m = 0; m < 8; ++m)
#pragma unroll
            for (int j = 0; j < 4; ++j) {
                const int row = m * 16 + r4 + j;
                oc[(long)row * N + n * 16 + l15] = (bf16)fmaxf(acc[m][n][j] + bv, 0.0f);
            }
    }
#undef STG
#undef RDA
#undef RDB
#undef MFMA16
}

// ---------------- generic 128x128 bf16 GEMM (fp32 or bf16 out) ----------------
template <int RELU, int HASBIAS, int OUTBF>
__global__ __launch_bounds__(256, 2)
void gemm_bf16_kernel(const bf16* __restrict__ A, const bf16* __restrict__ Wt,
                      const float* __restrict__ bias, void* __restrict__ outv,
                      int Kloop, int lda, int ldb,
                      long a_zoff, long w_zoff, long b_cstride,
                      long out_rstride, long out_zoff)
{
    __shared__ __align__(16) bf16 As[128 * 64];
    __shared__ __align__(16) bf16 Bs[128 * 64];

    const int z  = blockIdx.z;
    const int m0 = blockIdx.x * 128;
    const int n0 = blockIdx.y * 128;
    const int t  = threadIdx.x;
    const int lane = t & 63, wave = t >> 6;
    const int wr = wave >> 1, wc = wave & 1;

    const bf16* Ac = A  + (long)z * a_zoff;
    const bf16* W  = Wt + (long)z * w_zoff;
    const long obase = (long)z * out_zoff + (long)m0 * out_rstride + n0;

    const int sr = t >> 3;
    const int sc = (t & 7) * 8;

    f32x4 acc[4][4] = {};

    for (int kt = 0; kt < Kloop / 64; ++kt) {
        const int k0 = kt * 64;
#pragma unroll
        for (int i = 0; i < 4; ++i)
            gload_lds16(Ac + (long)(m0 + i * 32 + sr) * lda + k0 + sc, &As[i * 2048 + wave * 512]);
#pragma unroll
        for (int i = 0; i < 4; ++i)
            gload_lds16(W + (long)(n0 + i * 32 + sr) * ldb + k0 + sc, &Bs[i * 2048 + wave * 512]);
        __syncthreads();

#pragma unroll
        for (int kk = 0; kk < 2; ++kk) {
            bf16x8 af[4], bfr[4];
#pragma unroll
            for (int m = 0; m < 4; ++m)
                af[m] = *(const bf16x8*)&As[(wr * 64 + m * 16 + (lane & 15)) * 64 + kk * 32 + (lane >> 4) * 8];
#pragma unroll
            for (int n = 0; n < 4; ++n)
                bfr[n] = *(const bf16x8*)&Bs[(wc * 64 + n * 16 + (lane & 15)) * 64 + kk * 32 + (lane >> 4) * 8];
#pragma unroll
            for (int m = 0; m < 4; ++m)
#pragma unroll
                for (int n = 0; n < 4; ++n)
                    acc[m][n] = __builtin_amdgcn_mfma_f32_16x16x32_bf16(af[m], bfr[n], acc[m][n], 0, 0, 0);
        }
        __syncthreads();
    }

    const int ci = lane & 15, r4 = (lane >> 4) * 4;
#pragma unroll
    for (int m = 0; m < 4; ++m)
#pragma unroll
        for (int n = 0; n < 4; ++n) {
            const int col = wc * 64 + n * 16 + ci;
            float bv = 0.f;
            if (HASBIAS) bv = bias[(long)z * b_cstride + n0 + col];
#pragma unroll
            for (int j = 0; j < 4; ++j) {
                const int row = wr * 64 + m * 16 + r4 + j;
                float v = acc[m][n][j] + bv;
                if (RELU) v = fmaxf(v, 0.0f);
                const long idx = obase + (long)row * out_rstride + col;
                if (OUTBF) ((bf16*)outv)[idx] = (bf16)v;
                else       ((float*)outv)[idx] = v;
            }
        }
}

// ---------------- fusion: l2-norm over C, concept prob, bottleneck (single pass) ----------------
__global__ void fuse_kernel(const float* __restrict__ cm, const bf16* __restrict__ lat,
                            bf16* __restrict__ bott)
{
    const int wave = threadIdx.x >> 6;
    const int l    = threadIdx.x & 63;
    const int b    = blockIdx.x * 4 + wave;
    const float* cmb = cm  + (size_t)b * 2048;
    const bf16*  lb  = lat + (size_t)b * 2048;

    float vc0[16], vc1[16], vl0[16], vl1[16];
    float sq0 = 0.f, sq1 = 0.f;
#pragma unroll
    for (int c = 0; c < 16; ++c) {
        float c0 = cmb[c * 128 + l], c1 = cmb[c * 128 + 64 + l];
        vc0[c] = c0; vc1[c] = c1;
        vl0[c] = (float)lb[c * 128 + l];
        vl1[c] = (float)lb[c * 128 + 64 + l];
        sq0 += c0 * c0; sq1 += c1 * c1;
    }
    const float rs0 = rsqrtf(fmaxf(sq0, 1e-12f));
    const float rs1 = rsqrtf(fmaxf(sq1, 1e-12f));
#pragma unroll
    for (int c = 0; c < 16; ++c) {
        const float cn0 = vc0[c] * rs0, cn1 = vc1[c] * rs1;
        float part = cn0 * vl0[c] + cn1 * vl1[c];
#pragma unroll
        for (int off = 32; off; off >>= 1) part += __shfl_xor(part, off);
        const float p = 1.0f / (1.0f + expf(-part));
        bott[(size_t)b * 1024 + c * 64 + l] = (bf16)(p * cn1 + (1.0f - p) * cn0);
    }
}

// ---------------- final: reduce z partials, relu, logits ----------------
__global__ void head2_kernel(const float* __restrict__ zp, const float* __restrict__ bgh,
                             const float* __restrict__ Wc, const float* __restrict__ bc,
                             float* __restrict__ out)
{
    __shared__ float zrow[128];
    const int b = blockIdx.x;
    const int t = threadIdx.x;
    if (t < 128) {
        float s = bgh[t];
#pragma unroll
        for (int ks = 0; ks < 8; ++ks) s += zp[(size_t)ks * 524288 + (size_t)b * 128 + t];
        zrow[t] = fmaxf(s, 0.0f);
    }
    __syncthreads();
    if (t < 200) {
        float acc = bc[t];
#pragma unroll 8
        for (int k = 0; k < 128; ++k) acc = fmaf(zrow[k], Wc[k * 200 + t], acc);
        out[(size_t)b * 200 + t] = acc;
    }
}

// ---------------- launch ----------------

extern "C" void kernel_launch(void* const* d_in, const int* in_sizes, int n_in,
                              void* d_out, int out_size, void* d_ws, size_t ws_size,
                              hipStream_t stream)
{
    (void)in_sizes; (void)n_in; (void)out_size; (void)ws_size;

    const float* x    = (const float*)d_in[0];
    const float* fp   = (const float*)d_in[1];
    const float* mean = (const float*)d_in[2];
    const float* Wg1  = (const float*)d_in[3];
    const float* bg1  = (const float*)d_in[4];
    const float* Wg2  = (const float*)d_in[5];
    const float* bg2  = (const float*)d_in[6];
    const float* Wf1  = (const float*)d_in[7];
    const float* bf1  = (const float*)d_in[8];
    const float* Wf2  = (const float*)d_in[9];
    const float* bf2  = (const float*)d_in[10];
    const float* Wgh  = (const float*)d_in[11];
    const float* bgh  = (const float*)d_in[12];
    const float* Wc   = (const float*)d_in[13];
    const float* bc   = (const float*)d_in[14];
    float* outp = (float*)d_out;

    char* p = (char*)d_ws;
    size_t off = 0;
    auto alloc = [&](size_t bytes) { void* r = p + off; off += (bytes + 255) & ~(size_t)255; return r; };
    bf16*  xbf    = (bf16*) alloc((size_t)4096 * 2048 * 2);
    bf16*  Wall   = (bf16*) alloc((size_t)16 * 768 * 2048 * 2);
    bf16*  Wg2T   = (bf16*) alloc((size_t)16 * 128 * 256 * 2);
    bf16*  Wf2T   = (bf16*) alloc((size_t)128 * 512 * 2);
    bf16*  WghT   = (bf16*) alloc((size_t)128 * 1024 * 2);
    float* corr_g = (float*)alloc((size_t)16 * 256 * 4);
    float* corr_f = (float*)alloc((size_t)16 * 512 * 4);
    bf16*  h      = (bf16*) alloc((size_t)16 * 4096 * 256 * 2);
    bf16*  hf     = (bf16*) alloc((size_t)16 * 4096 * 512 * 2);
    float* cm     = (float*)alloc((size_t)4096 * 2048 * 4);
    bf16*  lat    = (bf16*) alloc((size_t)4096 * 2048 * 2);
    bf16*  bott   = (bf16*) alloc((size_t)4096 * 1024 * 2);
    float* zp     = (float*)alloc((size_t)8 * 4096 * 128 * 4);

    hipMemsetAsync(corr_g, 0, (size_t)(16 * 256 + 16 * 512) * 4, stream);
    cvt_x<<<4096, 256, 0, stream>>>(x, xbf);

    // Wall rows 0-255 <- sigmoid(fp[c]) * Wg1[c];  rows 256-767 <- sigmoid(fp[c]) * Wf1
    prep_w<1, 1><<<dim3(8, 64, 16), 256, 0, stream>>>(
        Wg1, Wall, 2048, 256, (long)2048 * 256, (long)768 * 2048, fp, mean, corr_g);
    prep_w<1, 16><<<dim3(16, 64, 1), 256, 0, stream>>>(
        Wf1, Wall + (size_t)256 * 2048, 2048, 512, 0, (long)768 * 2048, fp, mean, corr_f);
    prep_w<0, 1><<<dim3(4, 8, 16), 256, 0, stream>>>(
        Wg2, Wg2T, 256, 128, (long)256 * 128, (long)256 * 128, nullptr, nullptr, nullptr);
    prep_w<0, 1><<<dim3(4, 16, 1), 256, 0, stream>>>(
        Wf2, Wf2T, 512, 128, 0, 0, nullptr, nullptr, nullptr);
    prep_w<0, 1><<<dim3(4, 32, 1), 256, 0, stream>>>(
        Wgh, WghT, 1024, 128, 0, 0, nullptr, nullptr, nullptr);

    // h = relu(x @ (g.Wg1) + bg1 + corr_g); hf = relu(x @ (g.Wf1) + bf1 + corr_f)
    gemm256<<<768, 512, 0, stream>>>(xbf, Wall, bg1, corr_g, bf1, corr_f, h, hf);

    // cm[b][c][l] = h[c] @ Wg2[c]^T + bg2[c]   (fp32 out)
    gemm_bf16_kernel<0, 1, 0><<<dim3(32, 1, 16), 256, 0, stream>>>(
        h, Wg2T, bg2, cm, 256, 256, 256, (long)4096 * 256, (long)128 * 256, 128, 2048, 128);
    // lat[b][c][l] = hf[c] @ Wf2^T + bf2       (bf16 out)
    gemm_bf16_kernel<0, 1, 1><<<dim3(32, 1, 16), 256, 0, stream>>>(
        hf, Wf2T, bf2, lat, 512, 512, 512, (long)4096 * 512, 0, 0, 2048, 128);

    fuse_kernel<<<1024, 256, 0, stream>>>(cm, lat, bott);

    // z partials: zp[ks][b][t]
    gemm_bf16_kernel<0, 0, 0><<<dim3(32, 1, 8), 256, 0, stream>>>(
        bott, WghT, nullptr, zp, 128, 1024, 1024, 128, 128, 0, 128, (long)4096 * 128);

    head2_kernel<<<4096, 256, 0, stream>>>(zp, bgh, Wc, bc, outp);
}